// Round 10
// baseline (928.874 us; speedup 1.0000x reference)
//
#include <hip/hip_runtime.h>
#include <cstdint>

typedef short short8 __attribute__((ext_vector_type(8)));
typedef float f32x16 __attribute__((ext_vector_type(16)));

// Problem constants
#define NB 4
#define NN 4096
#define ND 576
#define BIGI 0x7FFFFFFF
#define NSLOT 32

// ws layout: A_hi (bf16) [b][tile128][kc18][512 chunks of 16B] = 9437184 shorts,
// then A_lo same size; then (float units):
#define INVN_OFF 9437184
#define CANDV_OFF 9439488
// CANDV: [b][32 slots][4096 rows][3] floats = 1572864
#define CANDI_OFF 11012352
// CANDI same size; end = 12,585,216 floats = 50.34 MB (R8 used this size and fit)
// Chunk swizzle (baked into layout): chunk g = r*4 + c', source chunk
// c = c' ^ ((r>>1)&3), i.e. source k-span = c*8..c*8+7 of row r.

#define MFMA __builtin_amdgcn_mfma_f32_32x32x16_bf16

__device__ __forceinline__ unsigned short f2bf(float f) {
    unsigned u = __float_as_uint(f);
    u += 0x7FFFu + ((u >> 16) & 1u);   // round-to-nearest-even
    return (unsigned short)(u >> 16);
}

__device__ __forceinline__ void gload_lds16(const void* g, void* l) {
    __builtin_amdgcn_global_load_lds(
        (const __attribute__((address_space(1))) void*)g,
        (__attribute__((address_space(3))) void*)l, 16, 0, 0);
}

// Exact jax top_k comparator: bigger value wins; tie -> smaller index wins.
__device__ __forceinline__ void insert_cmp(float v, int m,
    float& v0, int& i0, float& v1, int& i1, float& v2, int& i2) {
    bool beat2 = (v > v2) || (v == v2 && m < i2);
    if (beat2) {
        bool beat1 = (v > v1) || (v == v1 && m < i1);
        if (beat1) {
            v2 = v1; i2 = i1;
            bool beat0 = (v > v0) || (v == v0 && m < i0);
            if (beat0) { v1 = v0; i1 = i0; v0 = v; i0 = m; }
            else       { v1 = v;  i1 = m; }
        } else { v2 = v; i2 = m; }
    }
}

// Kernel 1: per-(b,c) windowed sums of x^2 -> inv norms for the 9 kernel offsets.
__global__ __launch_bounds__(64) void norm_kernel(const float* __restrict__ x,
                                                  float* __restrict__ ws) {
    const int bc = blockIdx.x;          // b*64 + c
    const int lane = threadIdx.x;       // = column w
    const float* xp = x + ((size_t)bc << 12);
    float colsum = 0.f, v0 = 0.f, v63 = 0.f;
    for (int h = 0; h < 64; ++h) {
        const float val = xp[(h << 6) + lane];
        const float sq = val * val;
        colsum += sq;
        if (h == 0)  v0 = sq;
        if (h == 63) v63 = sq;
    }
    float total = colsum, row0 = v0, row63 = v63;
    #pragma unroll
    for (int o = 32; o > 0; o >>= 1) {
        total += __shfl_xor(total, o);
        row0  += __shfl_xor(row0, o);
        row63 += __shfl_xor(row63, o);
    }
    const float col0  = __shfl(colsum, 0);
    const float col63 = __shfl(colsum, 63);
    const float c00 = __shfl(v0, 0),  c0e = __shfl(v0, 63);
    const float ce0 = __shfl(v63, 0), cee = __shfl(v63, 63);
    if (lane < 9) {
        const int dh = lane / 3 - 1, dw = lane % 3 - 1;
        float S = total;
        if (dh == 1)  S -= row0;
        if (dh == -1) S -= row63;
        if (dw == 1)  S -= col0;
        if (dw == -1) S -= col63;
        if (dh == 1  && dw == 1)  S += c00;
        if (dh == 1  && dw == -1) S += c0e;
        if (dh == -1 && dw == 1)  S += ce0;
        if (dh == -1 && dw == -1) S += cee;
        float nrm = fmaxf(sqrtf(S), 1e-12f);
        ws[INVN_OFF + bc * 9 + lane] = 1.0f / nrm;
    }
}

// Kernel 2: split-bf16 materialization with baked chunk swizzle.
// blockIdx = (b*32+nt)*18+kc. Region = 512 chunks of 16B (8 bf16).
__global__ __launch_bounds__(256) void mat_kernel(const float* __restrict__ x,
                                                  float* __restrict__ ws) {
    const int bi = blockIdx.x;             // 2304 blocks
    const int b = bi / 576;
    const int rem = bi - b * 576;
    const int nt = rem / 18;
    const int kc = rem - nt * 18;
    unsigned short* AH = (unsigned short*)ws;
    unsigned short* AL = AH + 9437184;
    const float* invn = ws + INVN_OFF + b * 576;
    const int tid = threadIdx.x;
    #pragma unroll
    for (int hf2 = 0; hf2 < 2; ++hf2) {
        const int g = tid + hf2 * 256;     // output chunk 0..511
        const int row = g >> 2, cp = g & 3;
        const int c = cp ^ ((row >> 1) & 3);    // source chunk (swizzle)
        const int k0 = c * 8;
        const int n = nt * 128 + row;
        const int h = n >> 6, wc = n & 63;
        union { unsigned short us[8]; float4 f4; } uh, ul;
        #pragma unroll
        for (int jj = 0; jj < 8; ++jj) {
            const int d = kc * 32 + k0 + jj;
            const int ch = d / 9;
            const int p = d - ch * 9;
            const int rr = h + p / 3 - 1, s2 = wc + p % 3 - 1;
            float val = 0.f;
            if ((unsigned)rr < 64u && (unsigned)s2 < 64u)
                val = x[((size_t)(b * 64 + ch) << 12) + (rr << 6) + s2];
            val *= invn[d];
            const unsigned short hb = f2bf(val);
            const float hfv = __uint_as_float(((unsigned)hb) << 16);
            const unsigned short lb = f2bf(val - hfv);
            uh.us[jj] = hb; ul.us[jj] = lb;
        }
        ((float4*)AH)[(size_t)bi * 512 + g] = uh.f4;
        ((float4*)AL)[(size_t)bi * 512 + g] = ul.f4;
    }
}

__device__ __forceinline__ short8 ldfrag(const short* p) {
    union { short8 s8; float4 f4; } u;
    u.f4 = *(const float4*)p;
    return u.s8;
}

// Kernel 3: SYMMETRIC Gram R = A^T A (split-bf16 hh+hl+lh), fused top-3.
// R10 = symmetric halving on R4's PROVEN regime (Am-direct needs >=2
// blocks/CU co-resident: R4 = 50 MFMA/us/CU; R9 at 1 blk/CU = 21).
// Jobs: (n-region r 0..31 [128 rows], m-panel Q [256 cols]) with Q >= r>>1:
// 272/batch -> 1088 blocks (0.53x MFMA).  Block: 256 thr = 4 waves along m,
// wave tile 128n x 64m, acc[2][4] = 128 AGPR; V~100 -> alloc 128; 256/wave
// -> 2 waves/SIMD -> 2 blocks/CU co-resident; 1088 jobs backfill-balance.
// An (region r): LDS 2x16KB dbuf, issue-early, one __syncthreads/kc.
// Am (panel Q): direct global->VGPR.
// Candidates [b][32 slots][4096][3], slot = 128-col m-region:
//   n-side fold -> rows of r, slots 2Q (waves 0,1) / 2Q+1 (waves 2,3);
//   m-side fold (iff r < 2Q) -> rows of panel Q, slot r, via per-wave 32x32
//   rotate-swizzled LDS transpose (conflict-free; logic validated in R9).
// Coverage: row in region p gets slots >= p&~1 from n-side, < p&~1 from
// m-side -- complete, disjoint, written exactly once.
// C/D: m_part = (reg&3)+8*(reg>>2)+4*(lane>>5), n_part = lane&31  [HW-verified]
__global__ void __launch_bounds__(256, 2) gram_kernel(float* ws) {
    __shared__ short sm[16384];   // 32 KB: buf0 [0..8191], buf1 [8192..16383]
    // per buffer (shorts): AnH [0..4095], AnL [4096..8191]
    const int bx0 = blockIdx.x;
    const int bx = (bx0 & 7) * 136 + (bx0 >> 3);   // XCD swizzle (1088 = 8*136)
    const int b = bx / 272;
    int j = bx - b * 272;
    int r = 0;
    while (j >= 16 - (r >> 1)) { j -= 16 - (r >> 1); ++r; }  // unrank job
    const int Q = (r >> 1) + j;
    const int tid = threadIdx.x;
    const int w = tid >> 6, lane = tid & 63;
    const int l31 = lane & 31, kh2 = lane >> 5;
    const int wm = w;                 // 4 waves tile the 256 m-cols

    const unsigned short* AH = (const unsigned short*)ws;
    const unsigned short* AL = AH + 9437184;

    const int nReg = (b * 32 + r) * 18;                         // + kc
    const int mRegA = __builtin_amdgcn_readfirstlane(
        (b * 32 + 2 * Q + (wm >> 1)) * 18);                     // + kc

    // An frag LDS offsets within one buffer (shorts): H at 0, L at +4096.
    int boff[4][2];
    #pragma unroll
    for (int ni = 0; ni < 4; ++ni)
        #pragma unroll
        for (int h = 0; h < 2; ++h) {
            const int rr = ni * 32 + l31;            // 0..127
            const int c = kh2 + 2 * h;
            boff[ni][h] = rr * 32 + ((c ^ ((rr >> 1) & 3)) << 3);
        }
    // Am in-region lane offsets (direct global loads)
    int amoff[2][2];
    #pragma unroll
    for (int mi = 0; mi < 2; ++mi)
        #pragma unroll
        for (int h = 0; h < 2; ++h) {
            const int rl = (wm & 1) * 64 + mi * 32 + l31;   // 0..127
            const int c = kh2 + 2 * h;
            amoff[mi][h] = rl * 32 + ((c ^ ((rl >> 1) & 3)) << 3);
        }

    // prologue: stage An[kc=0] into buffer 0 (16 KB: 4 instr/thread)
    {
        const unsigned short* gH = AH + ((size_t)nReg << 12) + tid * 8;
        const unsigned short* gL = AL + ((size_t)nReg << 12) + tid * 8;
        gload_lds16(gH,        sm + tid * 8);
        gload_lds16(gH + 2048, sm + 2048 + tid * 8);
        gload_lds16(gL,        sm + 4096 + tid * 8);
        gload_lds16(gL + 2048, sm + 6144 + tid * 8);
    }
    __syncthreads();

    f32x16 acc[2][4];   // [mi][ni] -> 128 AGPRs
    #pragma unroll
    for (int mi = 0; mi < 2; ++mi)
        #pragma unroll
        for (int ni = 0; ni < 4; ++ni)
            #pragma unroll
            for (int e = 0; e < 16; ++e) acc[mi][ni][e] = 0.f;

    for (int kc = 0; kc < 18; ++kc) {
        const int cur = kc & 1;
        // issue next An stage first (overlaps with this kc's compute)
        if (kc < 17) {
            const unsigned short* gH = AH + ((size_t)(nReg + kc + 1) << 12) + tid * 8;
            const unsigned short* gL = AL + ((size_t)(nReg + kc + 1) << 12) + tid * 8;
            short* dstb = sm + ((cur ^ 1) << 13);
            gload_lds16(gH,        dstb + tid * 8);
            gload_lds16(gH + 2048, dstb + 2048 + tid * 8);
            gload_lds16(gL,        dstb + 4096 + tid * 8);
            gload_lds16(gL + 2048, dstb + 6144 + tid * 8);
        }
        // Am fragments: direct global->VGPR (wave-private; OK at 2 blk/CU)
        short8 amh[2][2], aml[2][2];   // [mi][h]
        {
            const short* rH = (const short*)(AH + ((size_t)(mRegA + kc) << 12));
            const short* rL = (const short*)(AL + ((size_t)(mRegA + kc) << 12));
            #pragma unroll
            for (int mi = 0; mi < 2; ++mi)
                #pragma unroll
                for (int h = 0; h < 2; ++h) {
                    amh[mi][h] = ldfrag(rH + amoff[mi][h]);
                    aml[mi][h] = ldfrag(rL + amoff[mi][h]);
                }
        }
        // An from LDS buffer cur + MFMA (per-acc limb order hh,hl,lh)
        const short* sb = sm + (cur << 13);
        #pragma unroll
        for (int h = 0; h < 2; ++h) {
            #pragma unroll
            for (int ni = 0; ni < 4; ++ni) {
                const short8 bh = ldfrag(sb + boff[ni][h]);
                const short8 bl = ldfrag(sb + boff[ni][h] + 4096);
                #pragma unroll
                for (int mi = 0; mi < 2; ++mi) {
                    acc[mi][ni] = MFMA(amh[mi][h], bh, acc[mi][ni], 0, 0, 0);
                    acc[mi][ni] = MFMA(amh[mi][h], bl, acc[mi][ni], 0, 0, 0);
                    acc[mi][ni] = MFMA(aml[mi][h], bh, acc[mi][ni], 0, 0, 0);
                }
            }
        }
        __syncthreads();
    }

    // ---- n-side fold: rows of region r (n = ni*32+l31), over wave's 64 m
    float t0v[4], t1v[4], t2v[4];
    int   t0i[4], t1i[4], t2i[4];
    #pragma unroll
    for (int i = 0; i < 4; ++i) {
        t0v[i] = t1v[i] = t2v[i] = -INFINITY;
        t0i[i] = t1i[i] = t2i[i] = BIGI;
    }
    #pragma unroll
    for (int ni = 0; ni < 4; ++ni)
        #pragma unroll
        for (int mi = 0; mi < 2; ++mi)
            #pragma unroll
            for (int v = 0; v < 16; ++v) {
                const int m = Q * 256 + wm * 64 + mi * 32
                            + (v & 3) + 8 * (v >> 2) + 4 * kh2;
                insert_cmp(acc[mi][ni][v], m,
                           t0v[ni], t0i[ni], t1v[ni], t1i[ni], t2v[ni], t2i[ni]);
            }
    #pragma unroll
    for (int ni = 0; ni < 4; ++ni) {
        const float pv0 = __shfl_xor(t0v[ni], 32), pv1 = __shfl_xor(t1v[ni], 32),
                    pv2 = __shfl_xor(t2v[ni], 32);
        const int pi0 = __shfl_xor(t0i[ni], 32), pi1 = __shfl_xor(t1i[ni], 32),
                  pi2 = __shfl_xor(t2i[ni], 32);
        insert_cmp(pv0, pi0, t0v[ni], t0i[ni], t1v[ni], t1i[ni], t2v[ni], t2i[ni]);
        insert_cmp(pv1, pi1, t0v[ni], t0i[ni], t1v[ni], t1i[ni], t2v[ni], t2i[ni]);
        insert_cmp(pv2, pi2, t0v[ni], t0i[ni], t1v[ni], t1i[ni], t2v[ni], t2i[ni]);
    }
    // stash n-side partials into buf1 (dead after last kc's barrier): 12 KB
    float* cv = (float*)sm + 4096;        // [w4][ni4][l32][3] = 1536 floats
    int*   ci = (int*)sm + 4096 + 1536;   // same shape
    if (kh2 == 0) {
        #pragma unroll
        for (int ni = 0; ni < 4; ++ni) {
            const int base = ((w * 4 + ni) * 32 + l31) * 3;
            cv[base] = t0v[ni]; cv[base + 1] = t1v[ni]; cv[base + 2] = t2v[ni];
            ci[base] = t0i[ni]; ci[base + 1] = t1i[ni]; ci[base + 2] = t2i[ni];
        }
    }

    int* wsi = (int*)ws;
    // ---- m-side fold (iff r < 2Q): rows of panel Q (wave's 64 m) over the
    // 128 n of region r.  Per-wave private 4 KB scratch in buf0; 32x32
    // transpose chunks with rotate swizzle col=(n+m32)&31 (conflict-free).
    if (r < 2 * Q) {
        float* scr = (float*)sm + w * 1024;     // 4 KB per wave (buf0)
        #pragma unroll
        for (int mi = 0; mi < 2; ++mi) {
            float m0v = -INFINITY, m1v = -INFINITY, m2v = -INFINITY;
            int m0i = BIGI, m1i = BIGI, m2i = BIGI;
            #pragma unroll
            for (int ni = 0; ni < 4; ++ni) {
                #pragma unroll
                for (int v = 0; v < 16; ++v) {
                    const int m32 = (v & 3) + 8 * (v >> 2) + 4 * kh2;
                    scr[m32 * 32 + ((l31 + m32) & 31)] = acc[mi][ni][v];
                }
                // lane reads its m-row (= l31); kh2 splits the 32-n scan
                #pragma unroll
                for (int jj = 0; jj < 16; ++jj) {
                    const int ncol = kh2 * 16 + jj;
                    const float val = scr[l31 * 32 + ((ncol + l31) & 31)];
                    const int n_g = r * 128 + ni * 32 + ncol;
                    insert_cmp(val, n_g, m0v, m0i, m1v, m1i, m2v, m2i);
                }
            }
            // merge kh2 halves (disjoint n-subsets folded per half)
            const float pv0 = __shfl_xor(m0v, 32), pv1 = __shfl_xor(m1v, 32),
                        pv2 = __shfl_xor(m2v, 32);
            const int pi0 = __shfl_xor(m0i, 32), pi1 = __shfl_xor(m1i, 32),
                      pi2 = __shfl_xor(m2i, 32);
            insert_cmp(pv0, pi0, m0v, m0i, m1v, m1i, m2v, m2i);
            insert_cmp(pv1, pi1, m0v, m0i, m1v, m1i, m2v, m2i);
            insert_cmp(pv2, pi2, m0v, m0i, m1v, m1i, m2v, m2i);
            if (kh2 == 0) {
                const int mu = Q * 256 + wm * 64 + mi * 32 + l31;  // global m-row
                const size_t o = ((size_t)(b * NSLOT + r) * NN + mu) * 3;
                ws[CANDV_OFF + o] = m0v; ws[CANDV_OFF + o + 1] = m1v;
                ws[CANDV_OFF + o + 2] = m2v;
                wsi[CANDI_OFF + o] = m0i; wsi[CANDI_OFF + o + 1] = m1i;
                wsi[CANDI_OFF + o + 2] = m2i;
            }
        }
    }

    // ---- n-side cross-wave merge: waves {0,1} -> slot 2Q, {2,3} -> slot 2Q+1
    __syncthreads();
    if (tid < 256) {
        const int g = tid >> 7;            // m-half -> slot 2Q+g
        const int row = tid & 127;         // n-row within region r
        const int ni = row >> 5, l = row & 31;
        float v0 = -INFINITY, v1 = -INFINITY, v2 = -INFINITY;
        int i0 = BIGI, i1 = BIGI, i2 = BIGI;
        #pragma unroll
        for (int ww = 0; ww < 2; ++ww) {
            const int w2 = g * 2 + ww;
            const int base = ((w2 * 4 + ni) * 32 + l) * 3;
            #pragma unroll
            for (int jj = 0; jj < 3; ++jj)
                insert_cmp(cv[base + jj], ci[base + jj], v0, i0, v1, i1, v2, i2);
        }
        const size_t o = ((size_t)(b * NSLOT + 2 * Q + g) * NN + r * 128 + row) * 3;
        ws[CANDV_OFF + o] = v0; ws[CANDV_OFF + o + 1] = v1; ws[CANDV_OFF + o + 2] = v2;
        wsi[CANDI_OFF + o] = i0; wsi[CANDI_OFF + o + 1] = i1; wsi[CANDI_OFF + o + 2] = i2;
    }
}

// Kernel 4: merge 32 slot candidates -> global top-3; 27-way attention. One wave per n.
__global__ __launch_bounds__(256) void attn_kernel(const float* __restrict__ x,
                                                   const float* __restrict__ ws,
                                                   float* __restrict__ out) {
    const int wid = threadIdx.x >> 6;
    const int lane = threadIdx.x & 63;
    const int gw = blockIdx.x * 4 + wid;   // 0..16383
    const int b = gw >> 12;
    const int n = gw & 4095;

    float v0 = -INFINITY, v1 = -INFINITY, v2 = -INFINITY;
    int i0 = BIGI, i1 = BIGI, i2 = BIGI;
    const int* wi = (const int*)ws;
    for (int s = 0; s < NSLOT; ++s) {
        const size_t o = ((size_t)(b * NSLOT + s) * NN + n) * 3;
        #pragma unroll
        for (int jj = 0; jj < 3; ++jj)
            insert_cmp(ws[CANDV_OFF + o + jj], wi[CANDI_OFF + o + jj], v0, i0, v1, i1, v2, i2);
    }
    const int idx3[3] = {i0, i1, i2};

    // per-lane feature meta for d = a*64 + lane  (torch reshape: K[...,a,c'] = xu[a*64+c'])
    int cc[9], dhh[9], dww[9];
    float inr[9];
    #pragma unroll
    for (int a = 0; a < 9; ++a) {
        const int d = a * 64 + lane;
        const int c = d / 9;
        const int p = d - c * 9;
        cc[a] = c; dhh[a] = p / 3 - 1; dww[a] = p - (p / 3) * 3 - 1;
        inr[a] = ws[INVN_OFF + b * ND + d];
    }
    const float q = x[((size_t)(b * 64 + lane) << 12) + n];

    float rv[27], sc[27];
    #pragma unroll
    for (int k = 0; k < 3; ++k) {
        const int m = idx3[k];
        const int hm = m >> 6, wmm = m & 63;
        #pragma unroll
        for (int a = 0; a < 9; ++a) {
            const int rr = hm + dhh[a], s2 = wmm + dww[a];
            float val = 0.f;
            if ((unsigned)rr < 64u && (unsigned)s2 < 64u)
                val = x[((size_t)(b * 64 + cc[a]) << 12) + (rr << 6) + s2];
            const float rc = val * inr[a];
            rv[k * 9 + a] = rc;
            float t = q * rc;
            #pragma unroll
            for (int o2 = 32; o2 > 0; o2 >>= 1) t += __shfl_xor(t, o2);
            sc[k * 9 + a] = t * 0.125f;   // / sqrt(64)
        }
    }
    float mx = -INFINITY;
    #pragma unroll
    for (int u = 0; u < 27; ++u) mx = fmaxf(mx, sc[u]);
    float sum = 0.f;
    #pragma unroll
    for (int u = 0; u < 27; ++u) { const float e = expf(sc[u] - mx); sc[u] = e; sum += e; }
    const float inv = 1.0f / sum;
    float o = 0.f;
    #pragma unroll
    for (int u = 0; u < 27; ++u) o += sc[u] * rv[u];
    out[((size_t)gw << 6) + lane] = o * inv;
}

extern "C" void kernel_launch(void* const* d_in, const int* in_sizes, int n_in,
                              void* d_out, int out_size, void* d_ws, size_t ws_size,
                              hipStream_t stream) {
    (void)in_sizes; (void)n_in; (void)out_size; (void)ws_size;
    const float* x = (const float*)d_in[0];
    float* ws = (float*)d_ws;
    float* out = (float*)d_out;

    hipLaunchKernelGGL(norm_kernel, dim3(NB * 64), dim3(64), 0, stream, x, ws);
    hipLaunchKernelGGL(mat_kernel, dim3(2304), dim3(256), 0, stream, x, ws);
    hipLaunchKernelGGL(gram_kernel, dim3(1088), dim3(256), 0, stream, ws);
    hipLaunchKernelGGL(attn_kernel, dim3(4096), dim3(256), 0, stream, x, ws, out);
}

// Round 11
// 615.009 us; speedup vs baseline: 1.5103x; 1.5103x over previous
//
#include <hip/hip_runtime.h>
#include <cstdint>

typedef short short8 __attribute__((ext_vector_type(8)));
typedef float f32x16 __attribute__((ext_vector_type(16)));

// Problem constants
#define NB 4
#define NN 4096
#define ND 576
#define BIGI 0x7FFFFFFF
#define NSLICE 4

// ws layout: A_hi (bf16) [b][tile128][kc18][512 chunks of 16B] = 9437184 shorts,
// then A_lo same size; then (float units):
#define INVN_OFF 9437184
#define CANDV_OFF 9439488
#define CANDI_OFF 9636096
// total = 9832704 floats = 39.33 MB
// Chunk swizzle (baked into layout): chunk g = r*4 + c', source chunk
// c = c' ^ ((r>>1)&3), i.e. source k-span = c*8..c*8+7 of row r.

#define MFMA __builtin_amdgcn_mfma_f32_32x32x16_bf16

__device__ __forceinline__ unsigned short f2bf(float f) {
    unsigned u = __float_as_uint(f);
    u += 0x7FFFu + ((u >> 16) & 1u);   // round-to-nearest-even
    return (unsigned short)(u >> 16);
}

__device__ __forceinline__ void gload_lds16(const void* g, void* l) {
    __builtin_amdgcn_global_load_lds(
        (const __attribute__((address_space(1))) void*)g,
        (__attribute__((address_space(3))) void*)l, 16, 0, 0);
}

// Exact jax top_k comparator: bigger value wins; tie -> smaller index wins.
__device__ __forceinline__ void insert_cmp(float v, int m,
    float& v0, int& i0, float& v1, int& i1, float& v2, int& i2) {
    bool beat2 = (v > v2) || (v == v2 && m < i2);
    if (beat2) {
        bool beat1 = (v > v1) || (v == v1 && m < i1);
        if (beat1) {
            v2 = v1; i2 = i1;
            bool beat0 = (v > v0) || (v == v0 && m < i0);
            if (beat0) { v1 = v0; i1 = i0; v0 = v; i0 = m; }
            else       { v1 = v;  i1 = m; }
        } else { v2 = v; i2 = m; }
    }
}

// Kernel 1: per-(b,c) windowed sums of x^2 -> inv norms for the 9 kernel offsets.
__global__ __launch_bounds__(64) void norm_kernel(const float* __restrict__ x,
                                                  float* __restrict__ ws) {
    const int bc = blockIdx.x;          // b*64 + c
    const int lane = threadIdx.x;       // = column w
    const float* xp = x + ((size_t)bc << 12);
    float colsum = 0.f, v0 = 0.f, v63 = 0.f;
    for (int h = 0; h < 64; ++h) {
        const float val = xp[(h << 6) + lane];
        const float sq = val * val;
        colsum += sq;
        if (h == 0)  v0 = sq;
        if (h == 63) v63 = sq;
    }
    float total = colsum, row0 = v0, row63 = v63;
    #pragma unroll
    for (int o = 32; o > 0; o >>= 1) {
        total += __shfl_xor(total, o);
        row0  += __shfl_xor(row0, o);
        row63 += __shfl_xor(row63, o);
    }
    const float col0  = __shfl(colsum, 0);
    const float col63 = __shfl(colsum, 63);
    const float c00 = __shfl(v0, 0),  c0e = __shfl(v0, 63);
    const float ce0 = __shfl(v63, 0), cee = __shfl(v63, 63);
    if (lane < 9) {
        const int dh = lane / 3 - 1, dw = lane % 3 - 1;
        float S = total;
        if (dh == 1)  S -= row0;
        if (dh == -1) S -= row63;
        if (dw == 1)  S -= col0;
        if (dw == -1) S -= col63;
        if (dh == 1  && dw == 1)  S += c00;
        if (dh == 1  && dw == -1) S += c0e;
        if (dh == -1 && dw == 1)  S += ce0;
        if (dh == -1 && dw == -1) S += cee;
        float nrm = fmaxf(sqrtf(S), 1e-12f);
        ws[INVN_OFF + bc * 9 + lane] = 1.0f / nrm;
    }
}

// Kernel 2: split-bf16 materialization with baked chunk swizzle.
// blockIdx = (b*32+nt)*18+kc. Region = 512 chunks of 16B (8 bf16).
__global__ __launch_bounds__(256) void mat_kernel(const float* __restrict__ x,
                                                  float* __restrict__ ws) {
    const int bi = blockIdx.x;             // 2304 blocks
    const int b = bi / 576;
    const int rem = bi - b * 576;
    const int nt = rem / 18;
    const int kc = rem - nt * 18;
    unsigned short* AH = (unsigned short*)ws;
    unsigned short* AL = AH + 9437184;
    const float* invn = ws + INVN_OFF + b * 576;
    const int tid = threadIdx.x;
    #pragma unroll
    for (int hf2 = 0; hf2 < 2; ++hf2) {
        const int g = tid + hf2 * 256;     // output chunk 0..511
        const int row = g >> 2, cp = g & 3;
        const int c = cp ^ ((row >> 1) & 3);    // source chunk (swizzle)
        const int k0 = c * 8;
        const int n = nt * 128 + row;
        const int h = n >> 6, wc = n & 63;
        union { unsigned short us[8]; float4 f4; } uh, ul;
        #pragma unroll
        for (int j = 0; j < 8; ++j) {
            const int d = kc * 32 + k0 + j;
            const int ch = d / 9;
            const int p = d - ch * 9;
            const int r = h + p / 3 - 1, s2 = wc + p % 3 - 1;
            float val = 0.f;
            if ((unsigned)r < 64u && (unsigned)s2 < 64u)
                val = x[((size_t)(b * 64 + ch) << 12) + (r << 6) + s2];
            val *= invn[d];
            const unsigned short hb = f2bf(val);
            const float hfv = __uint_as_float(((unsigned)hb) << 16);
            const unsigned short lb = f2bf(val - hfv);
            uh.us[j] = hb; ul.us[j] = lb;
        }
        ((float4*)AH)[(size_t)bi * 512 + g] = uh.f4;
        ((float4*)AL)[(size_t)bi * 512 + g] = ul.f4;
    }
}

__device__ __forceinline__ short8 ldfrag(const short* p) {
    union { short8 s8; float4 f4; } u;
    u.f4 = *(const float4*)p;
    return u.s8;
}

// Kernel 3: R = A^T A via split-bf16 MFMA (hh + hl + lh), fused top-3.
// R11 = R7 (session champion, gram 491 us) + SPILL FIX.  R7's forced V<=64
// (__launch_bounds__(256,4), 4 waves/SIMD -- the one gate that measurably
// helped) spilled ~970 B/thread (WRITE_SIZE 64->254 MB).  Fix: SERIALIZE the
// mi loop so only ONE Am limb-pair (8 V) is live at a time instead of two
// (16 V); B fragments re-read per mi (16 vs 8 ds_read/wave/kc -- LDS has
// ample headroom).  Per-acc limb order stays hh,hl,lh per h -> bitwise
// identical results.  Everything else identical to R7:
// Grid 1024 = b(4) x nt(64: 64-row n-panels) x s(4) -> 4 blocks/CU.
// Block: 256 thr = 4 waves along m; per mt covers 64n x 256m, mt=0..3 over
// the 1024-m slice.  An (shared): LDS, 2 x 8KB double buffer, issue-early,
// one __syncthreads per kc.  Am (wave-private): direct global->VGPR,
// region bases readfirstlane'd to SGPR.
// C/D: m_part = (reg&3)+8*(reg>>2)+4*(lane>>5), n_part = lane&31  [HW-verified]
__global__ void __launch_bounds__(256, 4) gram_kernel(float* ws) {
    __shared__ short sm[8192];   // 16 KB: buf0 {AnH[2048] AnL[2048]}, buf1 same
    const int bx0 = blockIdx.x;
    const int bx = ((bx0 & 7) << 7) | (bx0 >> 3);   // XCD swizzle (1024 = 8*128, bijective)
    const int b  = bx >> 8;
    const int nt = (bx >> 2) & 63;     // 64-row n-panel
    const int s  = bx & 3;
    const int tid = threadIdx.x;
    const int w = tid >> 6, lane = tid & 63;
    const int l31 = lane & 31, kh2 = lane >> 5;

    const unsigned short* AH = (const unsigned short*)ws;
    const unsigned short* AL = AH + 9437184;

    const int nReg = (b * 32 + (nt >> 1)) * 18;     // 128-row region; + kc
    const int nHalf = (nt & 1) * 2048;              // 64-row half (shorts)

    // An frag LDS offsets within one buffer (shorts): H at 0, L at +2048.
    // frag(row r, src chunk c) at r*32 + ((c ^ ((r>>1)&3))<<3), c = kh2 + 2h
    int boff[2][2];
    #pragma unroll
    for (int ni = 0; ni < 2; ++ni)
        #pragma unroll
        for (int h = 0; h < 2; ++h) {
            const int r = ni * 32 + l31;            // 0..63
            const int c = kh2 + 2 * h;
            boff[ni][h] = r * 32 + ((c ^ ((r >> 1) & 3)) << 3);
        }

    float t0v[2], t1v[2], t2v[2];
    int   t0i[2], t1i[2], t2i[2];
    #pragma unroll
    for (int i = 0; i < 2; ++i) {
        t0v[i] = t1v[i] = t2v[i] = -INFINITY;
        t0i[i] = t1i[i] = t2i[i] = BIGI;
    }

    // prologue: stage An[kc=0] into buffer 0 (8 KB: 2 instr/thread)
    {
        const unsigned short* gH = AH + (size_t)nReg * 4096 + nHalf + tid * 8;
        const unsigned short* gL = AL + (size_t)nReg * 4096 + nHalf + tid * 8;
        gload_lds16(gH, sm + tid * 8);
        gload_lds16(gL, sm + 2048 + tid * 8);
    }
    __syncthreads();

    for (int mt = 0; mt < 4; ++mt) {
        // Am meta for this mt: wave w owns m-cols mt*256 + w*64 .. +63
        int rif[2], amoff[2][2];
        #pragma unroll
        for (int mi = 0; mi < 2; ++mi) {
            const int mrow = s * 1024 + mt * 256 + w * 64 + mi * 32 + l31;  // 0..4095
            // region index is wave-uniform: force into SGPR
            rif[mi] = __builtin_amdgcn_readfirstlane((b * 32 + (mrow >> 7)) * 18);
            const int rl = mrow & 127;
            #pragma unroll
            for (int h = 0; h < 2; ++h) {
                const int c = kh2 + 2 * h;
                amoff[mi][h] = rl * 32 + ((c ^ ((rl >> 1) & 3)) << 3);
            }
        }

        f32x16 acc[2][2];   // [mi][ni] -> 64 AGPRs
        #pragma unroll
        for (int mi = 0; mi < 2; ++mi)
            #pragma unroll
            for (int ni = 0; ni < 2; ++ni)
                #pragma unroll
                for (int e = 0; e < 16; ++e) acc[mi][ni][e] = 0.f;

        for (int kc = 0; kc < 18; ++kc) {
            const int cur = kc & 1;     // 18 even -> parity consistent across mt
            // issue next An stage first (overlaps with this kc's compute)
            if (!(mt == 3 && kc == 17)) {
                const int nk = (kc + 1 == 18) ? 0 : kc + 1;
                const unsigned short* gH = AH + (size_t)(nReg + nk) * 4096 + nHalf + tid * 8;
                const unsigned short* gL = AL + (size_t)(nReg + nk) * 4096 + nHalf + tid * 8;
                short* dstb = sm + ((cur ^ 1) << 12);
                gload_lds16(gH, dstb + tid * 8);
                gload_lds16(gL, dstb + 2048 + tid * 8);
            }
            const short* sb = sm + (cur << 12);
            #pragma unroll
            for (int h = 0; h < 2; ++h) {
                // SERIAL mi: only one Am limb-pair (8 V) live at a time.
                #pragma unroll
                for (int mi = 0; mi < 2; ++mi) {
                    const short* rH = (const short*)(AH + ((size_t)(rif[mi] + kc) << 12));
                    const short* rL = (const short*)(AL + ((size_t)(rif[mi] + kc) << 12));
                    const short8 amh = ldfrag(rH + amoff[mi][h]);
                    const short8 aml = ldfrag(rL + amoff[mi][h]);
                    #pragma unroll
                    for (int ni = 0; ni < 2; ++ni) {
                        const short8 bh = ldfrag(sb + boff[ni][h]);
                        const short8 bl = ldfrag(sb + boff[ni][h] + 2048);
                        acc[mi][ni] = MFMA(amh, bh, acc[mi][ni], 0, 0, 0);
                        acc[mi][ni] = MFMA(amh, bl, acc[mi][ni], 0, 0, 0);
                        acc[mi][ni] = MFMA(aml, bh, acc[mi][ni], 0, 0, 0);
                    }
                }
            }
            // one barrier per kc: prior reads of buf cur drained before re-stage;
            // staged buf cur^1 complete (vmcnt drained by barrier) for kc+1.
            __syncthreads();
        }
        // fold acc into per-lane top-3 (per ni; n = ni*32 + l31)
        const int mbase = s * 1024 + mt * 256 + w * 64 + (kh2 << 2);
        #pragma unroll
        for (int ni = 0; ni < 2; ++ni)
            #pragma unroll
            for (int mi = 0; mi < 2; ++mi)
                #pragma unroll
                for (int v = 0; v < 16; ++v) {
                    const int m = mbase + mi * 32 + (v & 3) + 8 * (v >> 2);
                    insert_cmp(acc[mi][ni][v], m,
                               t0v[ni], t0i[ni], t1v[ni], t1i[ni], t2v[ni], t2i[ni]);
                }
    }

    // merge the two kh2 halves (same n, disjoint m) via shfl
    #pragma unroll
    for (int ni = 0; ni < 2; ++ni) {
        const float pv0 = __shfl_xor(t0v[ni], 32);
        const float pv1 = __shfl_xor(t1v[ni], 32);
        const float pv2 = __shfl_xor(t2v[ni], 32);
        const int pi0 = __shfl_xor(t0i[ni], 32);
        const int pi1 = __shfl_xor(t1i[ni], 32);
        const int pi2 = __shfl_xor(t2i[ni], 32);
        insert_cmp(pv0, pi0, t0v[ni], t0i[ni], t1v[ni], t1i[ni], t2v[ni], t2i[ni]);
        insert_cmp(pv1, pi1, t0v[ni], t0i[ni], t1v[ni], t1i[ni], t2v[ni], t2i[ni]);
        insert_cmp(pv2, pi2, t0v[ni], t0i[ni], t1v[ni], t1i[ni], t2v[ni], t2i[ni]);
    }
    // cross-wave merge through LDS (4 waves share the 64 n-rows, disjoint m)
    __syncthreads();
    float* cv = (float*)sm;              // [w4][ni2][l32][3] floats (3 KB)
    int*   ci = (int*)sm + 768;          // same shape (3 KB)
    if (kh2 == 0) {
        #pragma unroll
        for (int ni = 0; ni < 2; ++ni) {
            const int base = ((w * 2 + ni) * 32 + l31) * 3;
            cv[base] = t0v[ni]; cv[base + 1] = t1v[ni]; cv[base + 2] = t2v[ni];
            ci[base] = t0i[ni]; ci[base + 1] = t1i[ni]; ci[base + 2] = t2i[ni];
        }
    }
    __syncthreads();
    if (tid < 64) {
        const int ni = tid >> 5, l = tid & 31;
        float v0 = -INFINITY, v1 = -INFINITY, v2 = -INFINITY;
        int i0 = BIGI, i1 = BIGI, i2 = BIGI;
        #pragma unroll
        for (int w2 = 0; w2 < 4; ++w2) {
            const int base = ((w2 * 2 + ni) * 32 + l) * 3;
            #pragma unroll
            for (int j = 0; j < 3; ++j)
                insert_cmp(cv[base + j], ci[base + j], v0, i0, v1, i1, v2, i2);
        }
        const int n_global = nt * 64 + tid;
        const size_t o = ((size_t)(b * NSLICE + s) * NN + n_global) * 3;
        ws[CANDV_OFF + o] = v0; ws[CANDV_OFF + o + 1] = v1; ws[CANDV_OFF + o + 2] = v2;
        int* wi = (int*)ws;
        wi[CANDI_OFF + o] = i0; wi[CANDI_OFF + o + 1] = i1; wi[CANDI_OFF + o + 2] = i2;
    }
}

// Kernel 4: merge slice candidates -> global top-3; 27-way attention. One wave per n.
__global__ __launch_bounds__(256) void attn_kernel(const float* __restrict__ x,
                                                   const float* __restrict__ ws,
                                                   float* __restrict__ out) {
    const int wid = threadIdx.x >> 6;
    const int lane = threadIdx.x & 63;
    const int gw = blockIdx.x * 4 + wid;   // 0..16383
    const int b = gw >> 12;
    const int n = gw & 4095;

    float v0 = -INFINITY, v1 = -INFINITY, v2 = -INFINITY;
    int i0 = BIGI, i1 = BIGI, i2 = BIGI;
    const int* wi = (const int*)ws;
    #pragma unroll
    for (int s = 0; s < NSLICE; ++s) {
        const size_t o = ((size_t)(b * NSLICE + s) * NN + n) * 3;
        #pragma unroll
        for (int j = 0; j < 3; ++j)
            insert_cmp(ws[CANDV_OFF + o + j], wi[CANDI_OFF + o + j], v0, i0, v1, i1, v2, i2);
    }
    const int idx3[3] = {i0, i1, i2};

    // per-lane feature meta for d = a*64 + lane  (torch reshape: K[...,a,c'] = xu[a*64+c'])
    int cc[9], dhh[9], dww[9];
    float inr[9];
    #pragma unroll
    for (int a = 0; a < 9; ++a) {
        const int d = a * 64 + lane;
        const int c = d / 9;
        const int p = d - c * 9;
        cc[a] = c; dhh[a] = p / 3 - 1; dww[a] = p - (p / 3) * 3 - 1;
        inr[a] = ws[INVN_OFF + b * ND + d];
    }
    const float q = x[((size_t)(b * 64 + lane) << 12) + n];

    float rv[27], sc[27];
    #pragma unroll
    for (int k = 0; k < 3; ++k) {
        const int m = idx3[k];
        const int hm = m >> 6, wm = m & 63;
        #pragma unroll
        for (int a = 0; a < 9; ++a) {
            const int r = hm + dhh[a], s2 = wm + dww[a];
            float val = 0.f;
            if ((unsigned)r < 64u && (unsigned)s2 < 64u)
                val = x[((size_t)(b * 64 + cc[a]) << 12) + (r << 6) + s2];
            const float rr = val * inr[a];
            rv[k * 9 + a] = rr;
            float t = q * rr;
            #pragma unroll
            for (int o2 = 32; o2 > 0; o2 >>= 1) t += __shfl_xor(t, o2);
            sc[k * 9 + a] = t * 0.125f;   // / sqrt(64)
        }
    }
    float mx = -INFINITY;
    #pragma unroll
    for (int u = 0; u < 27; ++u) mx = fmaxf(mx, sc[u]);
    float sum = 0.f;
    #pragma unroll
    for (int u = 0; u < 27; ++u) { const float e = expf(sc[u] - mx); sc[u] = e; sum += e; }
    const float inv = 1.0f / sum;
    float o = 0.f;
    #pragma unroll
    for (int u = 0; u < 27; ++u) o += sc[u] * rv[u];
    out[((size_t)gw << 6) + lane] = o * inv;
}

extern "C" void kernel_launch(void* const* d_in, const int* in_sizes, int n_in,
                              void* d_out, int out_size, void* d_ws, size_t ws_size,
                              hipStream_t stream) {
    (void)in_sizes; (void)n_in; (void)out_size; (void)ws_size;
    const float* x = (const float*)d_in[0];
    float* ws = (float*)d_ws;
    float* out = (float*)d_out;

    hipLaunchKernelGGL(norm_kernel, dim3(NB * 64), dim3(64), 0, stream, x, ws);
    hipLaunchKernelGGL(mat_kernel, dim3(2304), dim3(256), 0, stream, x, ws);
    hipLaunchKernelGGL(gram_kernel, dim3(1024), dim3(256), 0, stream, ws);
    hipLaunchKernelGGL(attn_kernel, dim3(4096), dim3(256), 0, stream, x, ws, out);
}

// Round 12
// 591.811 us; speedup vs baseline: 1.5695x; 1.0392x over previous
//
#include <hip/hip_runtime.h>
#include <cstdint>

typedef short short8 __attribute__((ext_vector_type(8)));
typedef float f32x16 __attribute__((ext_vector_type(16)));

// Problem constants
#define NB 4
#define NN 4096
#define ND 576
#define BIGI 0x7FFFFFFF
#define NSLICE 4

// ws layout: A_hi (bf16) [b][tile128][kc18][512 chunks of 16B] = 9437184 shorts,
// then A_lo same size; then (float units):
#define INVN_OFF 9437184
#define CANDV_OFF 9439488
#define CANDI_OFF 9636096
// total = 9832704 floats = 39.33 MB
// Chunk swizzle (baked into layout): chunk g = r*4 + c', source chunk
// c = c' ^ ((r>>1)&3), i.e. source k-span = c*8..c*8+7 of row r.

#define MFMA __builtin_amdgcn_mfma_f32_32x32x16_bf16

__device__ __forceinline__ unsigned short f2bf(float f) {
    unsigned u = __float_as_uint(f);
    u += 0x7FFFu + ((u >> 16) & 1u);   // round-to-nearest-even
    return (unsigned short)(u >> 16);
}

__device__ __forceinline__ void gload_lds16(const void* g, void* l) {
    __builtin_amdgcn_global_load_lds(
        (const __attribute__((address_space(1))) void*)g,
        (__attribute__((address_space(3))) void*)l, 16, 0, 0);
}

// Exact jax top_k comparator: bigger value wins; tie -> smaller index wins.
__device__ __forceinline__ void insert_cmp(float v, int m,
    float& v0, int& i0, float& v1, int& i1, float& v2, int& i2) {
    bool beat2 = (v > v2) || (v == v2 && m < i2);
    if (beat2) {
        bool beat1 = (v > v1) || (v == v1 && m < i1);
        if (beat1) {
            v2 = v1; i2 = i1;
            bool beat0 = (v > v0) || (v == v0 && m < i0);
            if (beat0) { v1 = v0; i1 = i0; v0 = v; i0 = m; }
            else       { v1 = v;  i1 = m; }
        } else { v2 = v; i2 = m; }
    }
}

// Kernel 1: per-(b,c) windowed sums of x^2 -> inv norms for the 9 kernel offsets.
__global__ __launch_bounds__(64) void norm_kernel(const float* __restrict__ x,
                                                  float* __restrict__ ws) {
    const int bc = blockIdx.x;          // b*64 + c
    const int lane = threadIdx.x;       // = column w
    const float* xp = x + ((size_t)bc << 12);
    float colsum = 0.f, v0 = 0.f, v63 = 0.f;
    for (int h = 0; h < 64; ++h) {
        const float val = xp[(h << 6) + lane];
        const float sq = val * val;
        colsum += sq;
        if (h == 0)  v0 = sq;
        if (h == 63) v63 = sq;
    }
    float total = colsum, row0 = v0, row63 = v63;
    #pragma unroll
    for (int o = 32; o > 0; o >>= 1) {
        total += __shfl_xor(total, o);
        row0  += __shfl_xor(row0, o);
        row63 += __shfl_xor(row63, o);
    }
    const float col0  = __shfl(colsum, 0);
    const float col63 = __shfl(colsum, 63);
    const float c00 = __shfl(v0, 0),  c0e = __shfl(v0, 63);
    const float ce0 = __shfl(v63, 0), cee = __shfl(v63, 63);
    if (lane < 9) {
        const int dh = lane / 3 - 1, dw = lane % 3 - 1;
        float S = total;
        if (dh == 1)  S -= row0;
        if (dh == -1) S -= row63;
        if (dw == 1)  S -= col0;
        if (dw == -1) S -= col63;
        if (dh == 1  && dw == 1)  S += c00;
        if (dh == 1  && dw == -1) S += c0e;
        if (dh == -1 && dw == 1)  S += ce0;
        if (dh == -1 && dw == -1) S += cee;
        float nrm = fmaxf(sqrtf(S), 1e-12f);
        ws[INVN_OFF + bc * 9 + lane] = 1.0f / nrm;
    }
}

// Kernel 2: split-bf16 materialization with baked chunk swizzle.
// blockIdx = (b*32+nt)*18+kc. Region = 512 chunks of 16B (8 bf16).
__global__ __launch_bounds__(256) void mat_kernel(const float* __restrict__ x,
                                                  float* __restrict__ ws) {
    const int bi = blockIdx.x;             // 2304 blocks
    const int b = bi / 576;
    const int rem = bi - b * 576;
    const int nt = rem / 18;
    const int kc = rem - nt * 18;
    unsigned short* AH = (unsigned short*)ws;
    unsigned short* AL = AH + 9437184;
    const float* invn = ws + INVN_OFF + b * 576;
    const int tid = threadIdx.x;
    #pragma unroll
    for (int hf2 = 0; hf2 < 2; ++hf2) {
        const int g = tid + hf2 * 256;     // output chunk 0..511
        const int row = g >> 2, cp = g & 3;
        const int c = cp ^ ((row >> 1) & 3);    // source chunk (swizzle)
        const int k0 = c * 8;
        const int n = nt * 128 + row;
        const int h = n >> 6, wc = n & 63;
        union { unsigned short us[8]; float4 f4; } uh, ul;
        #pragma unroll
        for (int j = 0; j < 8; ++j) {
            const int d = kc * 32 + k0 + j;
            const int ch = d / 9;
            const int p = d - ch * 9;
            const int r = h + p / 3 - 1, s2 = wc + p % 3 - 1;
            float val = 0.f;
            if ((unsigned)r < 64u && (unsigned)s2 < 64u)
                val = x[((size_t)(b * 64 + ch) << 12) + (r << 6) + s2];
            val *= invn[d];
            const unsigned short hb = f2bf(val);
            const float hfv = __uint_as_float(((unsigned)hb) << 16);
            const unsigned short lb = f2bf(val - hfv);
            uh.us[j] = hb; ul.us[j] = lb;
        }
        ((float4*)AH)[(size_t)bi * 512 + g] = uh.f4;
        ((float4*)AL)[(size_t)bi * 512 + g] = ul.f4;
    }
}

__device__ __forceinline__ short8 ldfrag(const short* p) {
    union { short8 s8; float4 f4; } u;
    u.f4 = *(const float4*)p;
    return u.s8;
}

// Kernel 3: R = A^T A via split-bf16 MFMA (hh + hl + lh), fused top-3.
// R12 = R11 champion + VMEM ISSUE-ORDER FIX.  vmcnt retires IN ISSUE ORDER
// (ISA 8; m135): since R4, staging gload_lds was issued BEFORE the Am global
// loads, so the s_waitcnt needed to consume Am forced the next-kc staging to
// complete too -- the An stage sat on the critical path of EVERY kc despite
// "issue-early".  Fix: issue the 8 Am loads FIRST (oldest in queue), then
// the 2 staging gload_lds (newest; drained only at the end-of-kc barrier,
// by which time the whole compute phase has covered their latency).  One
// sched_barrier(0) pins the order against compiler sinking.
// Compute is parallel-mi (8 B ds_reads/wave/kc, as R7).  Per-acc limb order
// h0:(hh,hl,lh),h1:(hh,hl,lh) -- bitwise identical results.
// Everything else identical to R11:
// Grid 1024 = b(4) x nt(64: 64-row n-panels) x s(4) -> 4 blocks/CU.
// Block: 256 thr = 4 waves along m; per mt covers 64n x 256m, mt=0..3 over
// the 1024-m slice.  An (shared): LDS, 2 x 8KB double buffer, one
// __syncthreads per kc.  Am (wave-private): direct global->VGPR, region
// bases readfirstlane'd to SGPR.  __launch_bounds__(256,4) (V<=64 gate).
// C/D: m_part = (reg&3)+8*(reg>>2)+4*(lane>>5), n_part = lane&31  [HW-verified]
__global__ void __launch_bounds__(256, 4) gram_kernel(float* ws) {
    __shared__ short sm[8192];   // 16 KB: buf0 {AnH[2048] AnL[2048]}, buf1 same
    const int bx0 = blockIdx.x;
    const int bx = ((bx0 & 7) << 7) | (bx0 >> 3);   // XCD swizzle (1024 = 8*128, bijective)
    const int b  = bx >> 8;
    const int nt = (bx >> 2) & 63;     // 64-row n-panel
    const int s  = bx & 3;
    const int tid = threadIdx.x;
    const int w = tid >> 6, lane = tid & 63;
    const int l31 = lane & 31, kh2 = lane >> 5;

    const unsigned short* AH = (const unsigned short*)ws;
    const unsigned short* AL = AH + 9437184;

    const int nReg = (b * 32 + (nt >> 1)) * 18;     // 128-row region; + kc
    const int nHalf = (nt & 1) * 2048;              // 64-row half (shorts)

    // An frag LDS offsets within one buffer (shorts): H at 0, L at +2048.
    // frag(row r, src chunk c) at r*32 + ((c ^ ((r>>1)&3))<<3), c = kh2 + 2h
    int boff[2][2];
    #pragma unroll
    for (int ni = 0; ni < 2; ++ni)
        #pragma unroll
        for (int h = 0; h < 2; ++h) {
            const int r = ni * 32 + l31;            // 0..63
            const int c = kh2 + 2 * h;
            boff[ni][h] = r * 32 + ((c ^ ((r >> 1) & 3)) << 3);
        }

    float t0v[2], t1v[2], t2v[2];
    int   t0i[2], t1i[2], t2i[2];
    #pragma unroll
    for (int i = 0; i < 2; ++i) {
        t0v[i] = t1v[i] = t2v[i] = -INFINITY;
        t0i[i] = t1i[i] = t2i[i] = BIGI;
    }

    // prologue: stage An[kc=0] into buffer 0 (8 KB: 2 instr/thread)
    {
        const unsigned short* gH = AH + (size_t)nReg * 4096 + nHalf + tid * 8;
        const unsigned short* gL = AL + (size_t)nReg * 4096 + nHalf + tid * 8;
        gload_lds16(gH, sm + tid * 8);
        gload_lds16(gL, sm + 2048 + tid * 8);
    }
    __syncthreads();

    for (int mt = 0; mt < 4; ++mt) {
        // Am meta for this mt: wave w owns m-cols mt*256 + w*64 .. +63
        int rif[2], amoff[2][2];
        #pragma unroll
        for (int mi = 0; mi < 2; ++mi) {
            const int mrow = s * 1024 + mt * 256 + w * 64 + mi * 32 + l31;  // 0..4095
            // region index is wave-uniform: force into SGPR
            rif[mi] = __builtin_amdgcn_readfirstlane((b * 32 + (mrow >> 7)) * 18);
            const int rl = mrow & 127;
            #pragma unroll
            for (int h = 0; h < 2; ++h) {
                const int c = kh2 + 2 * h;
                amoff[mi][h] = rl * 32 + ((c ^ ((rl >> 1) & 3)) << 3);
            }
        }

        f32x16 acc[2][2];   // [mi][ni] -> 64 AGPRs
        #pragma unroll
        for (int mi = 0; mi < 2; ++mi)
            #pragma unroll
            for (int ni = 0; ni < 2; ++ni)
                #pragma unroll
                for (int e = 0; e < 16; ++e) acc[mi][ni][e] = 0.f;

        for (int kc = 0; kc < 18; ++kc) {
            const int cur = kc & 1;     // 18 even -> parity consistent across mt
            // (1) Am fragments FIRST: oldest in the VMEM queue, so the
            // s_waitcnt that consumes them does NOT drain the staging below.
            short8 amh[2][2], aml[2][2];   // [mi][h]
            #pragma unroll
            for (int mi = 0; mi < 2; ++mi) {
                const short* rH = (const short*)(AH + ((size_t)(rif[mi] + kc) << 12));
                const short* rL = (const short*)(AL + ((size_t)(rif[mi] + kc) << 12));
                #pragma unroll
                for (int h = 0; h < 2; ++h) {
                    amh[mi][h] = ldfrag(rH + amoff[mi][h]);
                    aml[mi][h] = ldfrag(rL + amoff[mi][h]);
                }
            }
            __builtin_amdgcn_sched_barrier(0);   // pin: Am issues before staging
            // (2) staging for next kc AFTER Am: newest in queue; drained only
            // by the end-of-kc barrier, with the whole compute phase to land.
            if (!(mt == 3 && kc == 17)) {
                const int nk = (kc + 1 == 18) ? 0 : kc + 1;
                const unsigned short* gH = AH + (size_t)(nReg + nk) * 4096 + nHalf + tid * 8;
                const unsigned short* gL = AL + (size_t)(nReg + nk) * 4096 + nHalf + tid * 8;
                short* dstb = sm + ((cur ^ 1) << 12);
                gload_lds16(gH, dstb + tid * 8);
                gload_lds16(gL, dstb + 2048 + tid * 8);
            }
            // (3) compute: An from LDS buffer cur + MFMA (limb order hh,hl,lh)
            const short* sb = sm + (cur << 12);
            #pragma unroll
            for (int h = 0; h < 2; ++h)
                #pragma unroll
                for (int ni = 0; ni < 2; ++ni) {
                    const short8 bh = ldfrag(sb + boff[ni][h]);
                    const short8 bl = ldfrag(sb + boff[ni][h] + 2048);
                    #pragma unroll
                    for (int mi = 0; mi < 2; ++mi) {
                        acc[mi][ni] = MFMA(amh[mi][h], bh, acc[mi][ni], 0, 0, 0);
                        acc[mi][ni] = MFMA(amh[mi][h], bl, acc[mi][ni], 0, 0, 0);
                        acc[mi][ni] = MFMA(aml[mi][h], bh, acc[mi][ni], 0, 0, 0);
                    }
                }
            // one barrier per kc: prior reads of buf cur drained before re-stage;
            // staged buf cur^1 complete (vmcnt drained by barrier) for kc+1.
            __syncthreads();
        }
        // fold acc into per-lane top-3 (per ni; n = ni*32 + l31)
        const int mbase = s * 1024 + mt * 256 + w * 64 + (kh2 << 2);
        #pragma unroll
        for (int ni = 0; ni < 2; ++ni)
            #pragma unroll
            for (int mi = 0; mi < 2; ++mi)
                #pragma unroll
                for (int v = 0; v < 16; ++v) {
                    const int m = mbase + mi * 32 + (v & 3) + 8 * (v >> 2);
                    insert_cmp(acc[mi][ni][v], m,
                               t0v[ni], t0i[ni], t1v[ni], t1i[ni], t2v[ni], t2i[ni]);
                }
    }

    // merge the two kh2 halves (same n, disjoint m) via shfl
    #pragma unroll
    for (int ni = 0; ni < 2; ++ni) {
        const float pv0 = __shfl_xor(t0v[ni], 32);
        const float pv1 = __shfl_xor(t1v[ni], 32);
        const float pv2 = __shfl_xor(t2v[ni], 32);
        const int pi0 = __shfl_xor(t0i[ni], 32);
        const int pi1 = __shfl_xor(t1i[ni], 32);
        const int pi2 = __shfl_xor(t2i[ni], 32);
        insert_cmp(pv0, pi0, t0v[ni], t0i[ni], t1v[ni], t1i[ni], t2v[ni], t2i[ni]);
        insert_cmp(pv1, pi1, t0v[ni], t0i[ni], t1v[ni], t1i[ni], t2v[ni], t2i[ni]);
        insert_cmp(pv2, pi2, t0v[ni], t0i[ni], t1v[ni], t1i[ni], t2v[ni], t2i[ni]);
    }
    // cross-wave merge through LDS (4 waves share the 64 n-rows, disjoint m)
    __syncthreads();
    float* cv = (float*)sm;              // [w4][ni2][l32][3] floats (3 KB)
    int*   ci = (int*)sm + 768;          // same shape (3 KB)
    if (kh2 == 0) {
        #pragma unroll
        for (int ni = 0; ni < 2; ++ni) {
            const int base = ((w * 2 + ni) * 32 + l31) * 3;
            cv[base] = t0v[ni]; cv[base + 1] = t1v[ni]; cv[base + 2] = t2v[ni];
            ci[base] = t0i[ni]; ci[base + 1] = t1i[ni]; ci[base + 2] = t2i[ni];
        }
    }
    __syncthreads();
    if (tid < 64) {
        const int ni = tid >> 5, l = tid & 31;
        float v0 = -INFINITY, v1 = -INFINITY, v2 = -INFINITY;
        int i0 = BIGI, i1 = BIGI, i2 = BIGI;
        #pragma unroll
        for (int w2 = 0; w2 < 4; ++w2) {
            const int base = ((w2 * 2 + ni) * 32 + l) * 3;
            #pragma unroll
            for (int j = 0; j < 3; ++j)
                insert_cmp(cv[base + j], ci[base + j], v0, i0, v1, i1, v2, i2);
        }
        const int n_global = nt * 64 + tid;
        const size_t o = ((size_t)(b * NSLICE + s) * NN + n_global) * 3;
        ws[CANDV_OFF + o] = v0; ws[CANDV_OFF + o + 1] = v1; ws[CANDV_OFF + o + 2] = v2;
        int* wi = (int*)ws;
        wi[CANDI_OFF + o] = i0; wi[CANDI_OFF + o + 1] = i1; wi[CANDI_OFF + o + 2] = i2;
    }
}

// Kernel 4: merge slice candidates -> global top-3; 27-way attention. One wave per n.
__global__ __launch_bounds__(256) void attn_kernel(const float* __restrict__ x,
                                                   const float* __restrict__ ws,
                                                   float* __restrict__ out) {
    const int wid = threadIdx.x >> 6;
    const int lane = threadIdx.x & 63;
    const int gw = blockIdx.x * 4 + wid;   // 0..16383
    const int b = gw >> 12;
    const int n = gw & 4095;

    float v0 = -INFINITY, v1 = -INFINITY, v2 = -INFINITY;
    int i0 = BIGI, i1 = BIGI, i2 = BIGI;
    const int* wi = (const int*)ws;
    #pragma unroll
    for (int s = 0; s < NSLICE; ++s) {
        const size_t o = ((size_t)(b * NSLICE + s) * NN + n) * 3;
        #pragma unroll
        for (int j = 0; j < 3; ++j)
            insert_cmp(ws[CANDV_OFF + o + j], wi[CANDI_OFF + o + j], v0, i0, v1, i1, v2, i2);
    }
    const int idx3[3] = {i0, i1, i2};

    // per-lane feature meta for d = a*64 + lane  (torch reshape: K[...,a,c'] = xu[a*64+c'])
    int cc[9], dhh[9], dww[9];
    float inr[9];
    #pragma unroll
    for (int a = 0; a < 9; ++a) {
        const int d = a * 64 + lane;
        const int c = d / 9;
        const int p = d - c * 9;
        cc[a] = c; dhh[a] = p / 3 - 1; dww[a] = p - (p / 3) * 3 - 1;
        inr[a] = ws[INVN_OFF + b * ND + d];
    }
    const float q = x[((size_t)(b * 64 + lane) << 12) + n];

    float rv[27], sc[27];
    #pragma unroll
    for (int k = 0; k < 3; ++k) {
        const int m = idx3[k];
        const int hm = m >> 6, wm = m & 63;
        #pragma unroll
        for (int a = 0; a < 9; ++a) {
            const int r = hm + dhh[a], s2 = wm + dww[a];
            float val = 0.f;
            if ((unsigned)r < 64u && (unsigned)s2 < 64u)
                val = x[((size_t)(b * 64 + cc[a]) << 12) + (r << 6) + s2];
            const float rr = val * inr[a];
            rv[k * 9 + a] = rr;
            float t = q * rr;
            #pragma unroll
            for (int o2 = 32; o2 > 0; o2 >>= 1) t += __shfl_xor(t, o2);
            sc[k * 9 + a] = t * 0.125f;   // / sqrt(64)
        }
    }
    float mx = -INFINITY;
    #pragma unroll
    for (int u = 0; u < 27; ++u) mx = fmaxf(mx, sc[u]);
    float sum = 0.f;
    #pragma unroll
    for (int u = 0; u < 27; ++u) { const float e = expf(sc[u] - mx); sc[u] = e; sum += e; }
    const float inv = 1.0f / sum;
    float o = 0.f;
    #pragma unroll
    for (int u = 0; u < 27; ++u) o += sc[u] * rv[u];
    out[((size_t)gw << 6) + lane] = o * inv;
}

extern "C" void kernel_launch(void* const* d_in, const int* in_sizes, int n_in,
                              void* d_out, int out_size, void* d_ws, size_t ws_size,
                              hipStream_t stream) {
    (void)in_sizes; (void)n_in; (void)out_size; (void)ws_size;
    const float* x = (const float*)d_in[0];
    float* ws = (float*)d_ws;
    float* out = (float*)d_out;

    hipLaunchKernelGGL(norm_kernel, dim3(NB * 64), dim3(64), 0, stream, x, ws);
    hipLaunchKernelGGL(mat_kernel, dim3(2304), dim3(256), 0, stream, x, ws);
    hipLaunchKernelGGL(gram_kernel, dim3(1024), dim3(256), 0, stream, ws);
    hipLaunchKernelGGL(attn_kernel, dim3(4096), dim3(256), 0, stream, x, ws, out);
}